// Round 4
// baseline (338.229 us; speedup 1.0000x reference)
//
#include <hip/hip_runtime.h>
#include <cstdint>
#include <cstddef>

// ---------------------------------------------------------------------------
// GenEdge R4:
//   cvt : f32 -> unit-norm f16 tiled layout, WRITE-coalesced mapping
//         (t = ks*64+q*16+i => block writes one contiguous 4KB span).
//   edge: 32-col waves (grid 4512), register double-buffered B prefetch
//         across di (loads for di+1 issued before compute of di, so the
//         ~1.2k-cyc epilogue hides the L2/L3 load latency). No LDS staging,
//         no barriers in the hot loop.
//   norm: divide by global max, zero 12-px border.
// ---------------------------------------------------------------------------

typedef _Float16 half8 __attribute__((ext_vector_type(8)));
typedef float    f32x4 __attribute__((ext_vector_type(4)));
typedef float    f32x4v __attribute__((ext_vector_type(4)));

#define HW   400
#define CCH  128
#define W16  416                 // padded width (26 groups of 16)
#define ROWE (W16*CCH)           // 53248 f16 elements per padded row
#define PAD  12
#define IEND 388                 // interior: [12, 388)

// f16 cube layout per row: [pg(26)][ks(4)][q(4)][i(16)][j(8)] elements
// offset = pg*2048 + ks*512 + q*128 + i*8 + j
// => a wave's B-frag load for (group, ks) is base + lane*16 B: one coalesced
//    global_load_dwordx4 per (sg, ks).

__device__ __forceinline__ float acos_fast(float x) {
  // Abramowitz-Stegun 4.4.45: |err| <= 6.7e-5 rad on [0,1]; reflect for x<0.
  float ax = fabsf(x);
  float s  = __builtin_amdgcn_sqrtf(1.0f - ax);
  float p  = fmaf(ax, -0.0187292994f, 0.0742610134f);
  p = fmaf(p, ax, -0.2121143967f);
  p = fmaf(p, ax,  1.5707287572f);
  float r = s * p;
  return (x >= 0.0f) ? r : (3.14159265359f - r);
}

// ---------------- Phase 1: convert + normalize (write-coalesced) -----------
__global__ void cvt_kernel(const float* __restrict__ cube,
                           _Float16* __restrict__ c16) {
  __shared__ float part[64];    // [i*4 + ks]
  int pg = blockIdx.x;          // 0..25 (pg 25 is all-pad)
  int r  = blockIdx.y;          // 0..399
  int t  = threadIdx.x;         // 0..255: t = ks*64 + q*16 + i
  int i  = t & 15;
  int q  = (t >> 4) & 3;
  int ks = t >> 6;
  int px = pg*16 + i;
  float v[8];
  if (px < HW) {
    const float* src = cube + ((size_t)(r*HW + px))*CCH + ks*32 + q*8;
    #pragma unroll
    for (int j = 0; j < 8; ++j) v[j] = src[j];
  } else {
    #pragma unroll
    for (int j = 0; j < 8; ++j) v[j] = 0.f;
  }
  float ss = 0.f;
  #pragma unroll
  for (int j = 0; j < 8; ++j) ss += v[j]*v[j];
  // reduce over q (lane bits 4..5 within the wave)
  ss += __shfl_xor(ss, 16);
  ss += __shfl_xor(ss, 32);
  if (q == 0) part[i*4 + ks] = ss;   // 2-way bank alias only (free)
  __syncthreads();
  f32x4v pp = *(const f32x4v*)&part[i*4];
  float tot = pp.x + pp.y + pp.z + pp.w;
  float sc = (tot > 0.f) ? rsqrtf(tot) : 0.f;
  half8 hv;
  #pragma unroll
  for (int j = 0; j < 8; ++j) hv[j] = (_Float16)(v[j]*sc);
  // out offset within group = ks*512 + q*128 + i*8 = 8*t -> contiguous 4KB
  *(half8*)(c16 + (size_t)r*ROWE + pg*2048 + t*8) = hv;
}

// ---------------- Phase 2: banded MFMA + SAD accumulation ----------------
__global__ __launch_bounds__(64, 2) void edge_kernel(
    const _Float16* __restrict__ c16,
    float* __restrict__ edge, unsigned* __restrict__ gmax) {
  // 4512 blocks = 8 XCDs x 564; each XCD gets a contiguous 47-row band.
  const int id = blockIdx.x;
  const int g  = (id & 7)*564 + (id >> 3);
  const int h  = g / 12 + PAD;           // 12..387
  const int wb = g - (g/12)*12;          // 0..11
  const int l  = threadIdx.x;
  const int c  = l & 15, q = l >> 4;
  const int w0 = PAD + 32*wb;
  const int g0 = 2*wb;                   // first B pixel-group (s0 = 32*wb)

  // A-frags: center pixels of row h.  A[m=lane&15][k=q*8+j]
  half8 A[2][4];
  #pragma unroll
  for (int t = 0; t < 2; ++t) {
    int px = w0 + 16*t + c;              // <= 395 < 400
    const _Float16* p = c16 + (size_t)h*ROWE + (px >> 4)*2048 + q*128 + (px & 15)*8;
    #pragma unroll
    for (int ks = 0; ks < 4; ++ks)
      A[t][ks] = *(const half8*)(p + ks*512);
  }

  const float cq = (float)(c - 4*q);     // dj-12 = 16d - 12 - rr + (c-4q)

  float gx[2][4], gy[2][4];
  #pragma unroll
  for (int t = 0; t < 2; ++t)
    #pragma unroll
    for (int rr = 0; rr < 4; ++rr) { gx[t][rr] = 0.f; gy[t][rr] = 0.f; }

  const _Float16* base = c16 + g0*2048 + l*8;

  half8 Ba[16], Bb[16];                  // [sg*4+ks], double-buffered

  auto loadB = [&](half8* B, int r) {
    const _Float16* rowB = base + (size_t)r*ROWE;
    #pragma unroll
    for (int sg = 0; sg < 4; ++sg)
      #pragma unroll
      for (int ks = 0; ks < 4; ++ks)
        B[sg*4+ks] = *(const half8*)(rowB + sg*2048 + ks*512);
  };

  auto compute = [&](int di, const half8* B) {
    // per-di weight coefficients, shared across both M-tiles
    const float ii  = (float)((di <= 12) ? di : 24 - di);
    const float sdi = (float)((di > 12) - (di < 12));
    const float dif = (float)(di - 12);
    float kx[12], ky[12];
    #pragma unroll
    for (int d = 0; d < 3; ++d)
      #pragma unroll
      for (int rr = 0; rr < 4; ++rr) {
        int j = d*4 + rr;
        float p  = cq + (float)(16*d - 12 - rr);     // dj - 12
        float ap = fabsf(p);
        float sg = fminf(fmaxf(p, -1.f), 1.f);       // sgn (p is integer)
        bool  ok = ap <= 12.f;
        kx[j] = ok ? fmaf(sg, ii, p) : 0.f;
        ky[j] = ok ? fmaf(sdi, 12.f - ap, dif) : 0.f;  // mnj = 12-|dj-12|
      }
    #pragma unroll
    for (int t = 0; t < 2; ++t) {
      f32x4 acc[3];
      #pragma unroll
      for (int d = 0; d < 3; ++d) acc[d] = (f32x4){0.f,0.f,0.f,0.f};
      #pragma unroll
      for (int ks = 0; ks < 4; ++ks)
        #pragma unroll
        for (int d = 0; d < 3; ++d)    // band: M-tile t uses s-groups t..t+2
          acc[d] = __builtin_amdgcn_mfma_f32_16x16x32_f16(
              A[t][ks], B[(t+d)*4+ks], acc[d], 0, 0, 0);
      #pragma unroll
      for (int d = 0; d < 3; ++d)
        #pragma unroll
        for (int rr = 0; rr < 4; ++rr) {
          int   j     = d*4 + rr;
          float ratio = acc[d][rr];    // already cos (unit vectors)
          ratio = fminf(fmaxf(ratio, -0.999999f), 0.999999f);
          float sad = acos_fast(ratio);
          gx[t][rr] = fmaf(sad, kx[j], gx[t][rr]);
          gy[t][rr] = fmaf(sad, ky[j], gy[t][rr]);
        }
    }
  };

  loadB(Ba, h - PAD);
  #pragma unroll 1
  for (int di = 0; di < 25; di += 2) {
    if (di + 1 < 25) loadB(Bb, h - PAD + di + 1);   // prefetch di+1
    compute(di, Ba);
    if (di + 1 < 25) {
      if (di + 2 < 25) loadB(Ba, h - PAD + di + 2); // prefetch di+2
      compute(di + 1, Bb);
    }
  }

  // reduce over c (lane bits 0..3) via butterfly; writers: lanes c == rr
  float e = 0.f;
  #pragma unroll
  for (int t = 0; t < 2; ++t)
    #pragma unroll
    for (int rr = 0; rr < 4; ++rr) {
      float sgx = gx[t][rr], sgy = gy[t][rr];
      #pragma unroll
      for (int m = 1; m < 16; m <<= 1) {
        sgx += __shfl_xor(sgx, m);
        sgy += __shfl_xor(sgy, m);
      }
      if (c == rr) {
        int w = w0 + 16*t + 4*q + rr;
        float v = fabsf(sgx) + fabsf(sgy);
        if (w < IEND) { edge[h*HW + w] = v; e = fmaxf(e, v); }
      }
    }
  #pragma unroll
  for (int off = 1; off < 64; off <<= 1) e = fmaxf(e, __shfl_xor(e, off));
  if (l == 0) atomicMax(gmax, __float_as_uint(e));  // e >= 0: uint order ok
}

// ---------------- Phase 3: normalize ----------------
__global__ void norm_kernel(const float* __restrict__ edge,
                            const unsigned* __restrict__ gmax,
                            float* __restrict__ out) {
  int idx = blockIdx.x*256 + threadIdx.x;
  if (idx >= HW*HW) return;
  int hh = idx / HW;
  int ww = idx - hh*HW;
  float mv = __uint_as_float(*gmax);
  float v = 0.f;
  if (hh >= PAD && hh < IEND && ww >= PAD && ww < IEND)
    v = edge[idx] / mv;
  out[idx] = v;
}

// ---------------- launch ----------------
extern "C" void kernel_launch(void* const* d_in, const int* in_sizes, int n_in,
                              void* d_out, int out_size, void* d_ws, size_t ws_size,
                              hipStream_t stream) {
  const float* cube = (const float*)d_in[0];   // (1,400,400,128) f32
  char* ws = (char*)d_ws;
  _Float16* c16   = (_Float16*)(ws);                    // 42,598,400 B
  float*    edgeb = (float*)(ws + 42598400);            //    640,000 B
  unsigned* gmax  = (unsigned*)(ws + 43238400);         //          4 B

  hipMemsetAsync(gmax, 0, 4, stream);
  cvt_kernel<<<dim3(26, 400), 256, 0, stream>>>(cube, c16);
  edge_kernel<<<4512, 64, 0, stream>>>(c16, edgeb, gmax);
  norm_kernel<<<(HW*HW + 255)/256, 256, 0, stream>>>(edgeb, gmax, (float*)d_out);
}

// Round 5
// 245.003 us; speedup vs baseline: 1.3805x; 1.3805x over previous
//
#include <hip/hip_runtime.h>
#include <cstdint>
#include <cstddef>

// ---------------------------------------------------------------------------
// GenEdge R5:
//   cvt    : f32 -> unit-norm f16 tiled layout (write-coalesced) + gmax=0.
//   edge   : 32-col waves, di range split across 2 blocks (grid 9024 ->
//            ~35 blocks/CU, 4 waves/SIMD at ~114 regs). Lean registers:
//            A in regs (32v), B per-ks batches (16v live), acc in AGPR (24).
//            No LDS, no barriers, no register double-buffer (R4's spill bug).
//            Partial gx/gy written per half to global.
//   combine: sum halves, e=|gx|+|gy| (border zeroed), block-max -> atomicMax.
//   norm   : divide by global max.
// ---------------------------------------------------------------------------

typedef _Float16 half8 __attribute__((ext_vector_type(8)));
typedef float    f32x4 __attribute__((ext_vector_type(4)));

#define HW   400
#define NP   (HW*HW)
#define CCH  128
#define W16  416                 // padded width (26 groups of 16)
#define ROWE (W16*CCH)           // 53248 f16 elements per padded row
#define PAD  12
#define IEND 388                 // interior: [12, 388)

// f16 cube layout per row: [pg(26)][ks(4)][q(4)][i(16)][j(8)] elements
// offset = pg*2048 + ks*512 + q*128 + i*8 + j
// => a wave's B-frag load for (group, ks) is base + lane*16 B: one coalesced
//    global_load_dwordx4 per (sg, ks).

__device__ __forceinline__ float acos_fast(float x) {
  // Abramowitz-Stegun 4.4.45: |err| <= 6.7e-5 rad on [0,1]; reflect for x<0.
  float ax = fabsf(x);
  float s  = __builtin_amdgcn_sqrtf(1.0f - ax);
  float p  = fmaf(ax, -0.0187292994f, 0.0742610134f);
  p = fmaf(p, ax, -0.2121143967f);
  p = fmaf(p, ax,  1.5707287572f);
  float r = s * p;
  return (x >= 0.0f) ? r : (3.14159265359f - r);
}

// ---------------- Phase 1: convert + normalize (write-coalesced) -----------
__global__ void cvt_kernel(const float* __restrict__ cube,
                           _Float16* __restrict__ c16,
                           unsigned* __restrict__ gmax) {
  __shared__ float part[64];    // [i*4 + ks]
  int pg = blockIdx.x;          // 0..25 (pg 25 is all-pad)
  int r  = blockIdx.y;          // 0..399
  int t  = threadIdx.x;         // 0..255: t = ks*64 + q*16 + i
  if (pg == 0 && r == 0 && t == 0) *gmax = 0u;   // every call (re-poisoned ws)
  int i  = t & 15;
  int q  = (t >> 4) & 3;
  int ks = t >> 6;
  int px = pg*16 + i;
  float v[8];
  if (px < HW) {
    const float* src = cube + ((size_t)(r*HW + px))*CCH + ks*32 + q*8;
    #pragma unroll
    for (int j = 0; j < 8; ++j) v[j] = src[j];
  } else {
    #pragma unroll
    for (int j = 0; j < 8; ++j) v[j] = 0.f;
  }
  float ss = 0.f;
  #pragma unroll
  for (int j = 0; j < 8; ++j) ss += v[j]*v[j];
  ss += __shfl_xor(ss, 16);
  ss += __shfl_xor(ss, 32);
  if (q == 0) part[i*4 + ks] = ss;
  __syncthreads();
  f32x4 pp = *(const f32x4*)&part[i*4];
  float tot = pp.x + pp.y + pp.z + pp.w;
  float sc = (tot > 0.f) ? rsqrtf(tot) : 0.f;
  half8 hv;
  #pragma unroll
  for (int j = 0; j < 8; ++j) hv[j] = (_Float16)(v[j]*sc);
  *(half8*)(c16 + (size_t)r*ROWE + pg*2048 + t*8) = hv;
}

// ---------------- Phase 2: banded MFMA + SAD partials ----------------
__global__ __launch_bounds__(64, 4) void edge_kernel(
    const _Float16* __restrict__ c16,
    float* __restrict__ gxp, float* __restrict__ gyp) {
  // 9024 blocks = 8 XCDs x 1128; each XCD gets a contiguous 47-row band
  // (rows reused across the 24 (wb,half) blocks per row -> L2 locality).
  const int id   = blockIdx.x;
  const int g    = (id & 7)*1128 + (id >> 3);
  const int gh   = g / 24;
  const int rem  = g - gh*24;
  const int h    = gh + PAD;             // 12..387
  const int wb   = rem >> 1;             // 0..11
  const int half = rem & 1;              // di range half
  const int l  = threadIdx.x;
  const int c  = l & 15, q = l >> 4;
  const int w0 = PAD + 32*wb;
  const int g0 = 2*wb;                   // first B pixel-group (s0 = 32*wb)

  // A-frags: center pixels of row h.  A[m=lane&15][k=q*8+j]
  half8 A[2][4];
  #pragma unroll
  for (int t = 0; t < 2; ++t) {
    int px = w0 + 16*t + c;              // <= 395 < 400
    const _Float16* p = c16 + (size_t)h*ROWE + (px >> 4)*2048 + q*128 + (px & 15)*8;
    #pragma unroll
    for (int ks = 0; ks < 4; ++ks)
      A[t][ks] = *(const half8*)(p + ks*512);
  }

  const float cq = (float)(c - 4*q);     // dj-12 = 16d - 12 - rr + (c-4q)

  float gx[2][4], gy[2][4];
  #pragma unroll
  for (int t = 0; t < 2; ++t)
    #pragma unroll
    for (int rr = 0; rr < 4; ++rr) { gx[t][rr] = 0.f; gy[t][rr] = 0.f; }

  const _Float16* bBase = c16 + g0*2048 + (size_t)l*8;
  const int diLo = half ? 13 : 0;
  const int diHi = half ? 25 : 13;

  #pragma unroll 1
  for (int di = diLo; di < diHi; ++di) {
    const int r = h + di - PAD;          // 0..399
    const _Float16* rowB = bBase + (size_t)r*ROWE;

    f32x4 acc[2][3];
    #pragma unroll
    for (int t = 0; t < 2; ++t)
      #pragma unroll
      for (int d = 0; d < 3; ++d) acc[t][d] = (f32x4){0.f,0.f,0.f,0.f};

    #pragma unroll
    for (int ks = 0; ks < 4; ++ks) {
      half8 B0 = *(const half8*)(rowB + 0*2048 + ks*512);
      half8 B1 = *(const half8*)(rowB + 1*2048 + ks*512);
      half8 B2 = *(const half8*)(rowB + 2*2048 + ks*512);
      half8 B3 = *(const half8*)(rowB + 3*2048 + ks*512);
      acc[0][0] = __builtin_amdgcn_mfma_f32_16x16x32_f16(A[0][ks], B0, acc[0][0], 0,0,0);
      acc[0][1] = __builtin_amdgcn_mfma_f32_16x16x32_f16(A[0][ks], B1, acc[0][1], 0,0,0);
      acc[0][2] = __builtin_amdgcn_mfma_f32_16x16x32_f16(A[0][ks], B2, acc[0][2], 0,0,0);
      acc[1][0] = __builtin_amdgcn_mfma_f32_16x16x32_f16(A[1][ks], B1, acc[1][0], 0,0,0);
      acc[1][1] = __builtin_amdgcn_mfma_f32_16x16x32_f16(A[1][ks], B2, acc[1][1], 0,0,0);
      acc[1][2] = __builtin_amdgcn_mfma_f32_16x16x32_f16(A[1][ks], B3, acc[1][2], 0,0,0);
    }

    // per-di weights: kx = (dj-12) + sgn(dj-12)*ii ; ky = (di-12) + sdi*mnj
    const float ii  = (float)((di <= 12) ? di : 24 - di);
    const float sdi = (float)((di > 12) - (di < 12));
    const float dif = (float)(di - 12);
    #pragma unroll
    for (int t = 0; t < 2; ++t)
      #pragma unroll
      for (int d = 0; d < 3; ++d)
        #pragma unroll
        for (int rr = 0; rr < 4; ++rr) {
          float p  = cq + (float)(16*d - 12 - rr);     // dj - 12 (integer)
          float ap = fabsf(p);
          float sg = fminf(fmaxf(p, -1.f), 1.f);       // sgn
          bool  ok = ap <= 12.f;
          float kx = ok ? fmaf(sg, ii, p) : 0.f;
          float ky = ok ? fmaf(sdi, 12.f - ap, dif) : 0.f;  // mnj = 12-|dj-12|
          float ratio = acc[t][d][rr];                 // cos (unit vectors)
          ratio = fminf(fmaxf(ratio, -0.999999f), 0.999999f);
          float sad = acos_fast(ratio);
          gx[t][rr] = fmaf(sad, kx, gx[t][rr]);
          gy[t][rr] = fmaf(sad, ky, gy[t][rr]);
        }
  }

  // reduce over c (lane bits 0..3); writer lanes c == rr store partials
  const int hoff = half*NP + h*HW;
  #pragma unroll
  for (int t = 0; t < 2; ++t)
    #pragma unroll
    for (int rr = 0; rr < 4; ++rr) {
      float sgx = gx[t][rr], sgy = gy[t][rr];
      #pragma unroll
      for (int m = 1; m < 16; m <<= 1) {
        sgx += __shfl_xor(sgx, m);
        sgy += __shfl_xor(sgy, m);
      }
      if (c == rr) {
        int w = w0 + 16*t + 4*q + rr;    // <= 395
        gxp[hoff + w] = sgx;
        gyp[hoff + w] = sgy;
      }
    }
}

// ---------------- Phase 3a: combine halves + global max ----------------
__global__ void combine_kernel(float* __restrict__ gxp,
                               const float* __restrict__ gyp,
                               unsigned* __restrict__ gmax) {
  __shared__ float wm[4];
  int idx = blockIdx.x*256 + threadIdx.x;      // 625*256 = NP exactly
  int hh = idx / HW;
  int ww = idx - hh*HW;
  float e = 0.f;
  if (hh >= PAD && hh < IEND && ww >= PAD && ww < IEND)
    e = fabsf(gxp[idx] + gxp[NP + idx]) + fabsf(gyp[idx] + gyp[NP + idx]);
  gxp[idx] = e;                                // edge buffer aliases gxp[0]
  float m = e;
  #pragma unroll
  for (int off = 1; off < 64; off <<= 1) m = fmaxf(m, __shfl_xor(m, off));
  if ((threadIdx.x & 63) == 0) wm[threadIdx.x >> 6] = m;
  __syncthreads();
  if (threadIdx.x == 0) {
    float mm = fmaxf(fmaxf(wm[0], wm[1]), fmaxf(wm[2], wm[3]));
    atomicMax(gmax, __float_as_uint(mm));      // e >= 0: uint order ok
  }
}

// ---------------- Phase 3b: normalize ----------------
__global__ void norm_kernel(const float* __restrict__ edge,
                            const unsigned* __restrict__ gmax,
                            float* __restrict__ out) {
  int idx = blockIdx.x*256 + threadIdx.x;
  float mv = __uint_as_float(*gmax);
  out[idx] = edge[idx] / mv;                   // border already 0
}

// ---------------- launch ----------------
extern "C" void kernel_launch(void* const* d_in, const int* in_sizes, int n_in,
                              void* d_out, int out_size, void* d_ws, size_t ws_size,
                              hipStream_t stream) {
  const float* cube = (const float*)d_in[0];   // (1,400,400,128) f32
  char* ws = (char*)d_ws;
  _Float16* c16  = (_Float16*)(ws);                     // 42,598,400 B
  float*    gxp  = (float*)(ws + 42598400);             // 2*NP floats
  float*    gyp  = (float*)(ws + 42598400 + 8*NP);      // 2*NP floats
  unsigned* gmax = (unsigned*)(ws + 42598400 + 16*NP);  // 4 B  (~45.2 MB total)

  cvt_kernel<<<dim3(26, 400), 256, 0, stream>>>(cube, c16, gmax);
  edge_kernel<<<9024, 64, 0, stream>>>(c16, gxp, gyp);
  combine_kernel<<<NP/256, 256, 0, stream>>>(gxp, gyp, gmax);
  norm_kernel<<<NP/256, 256, 0, stream>>>(gxp, gmax, (float*)d_out);
}